// Round 13
// baseline (583.900 us; speedup 1.0000x reference)
//
#include <hip/hip_runtime.h>

#define NN 100000
#define NE 1200000
#define NG 2048
#define VOCAB 10000
#define D 64
#define C 2

#define NBK 196      // coarse buckets of 512 nodes (dst >> 9)
#define BSH 9
#define SLOT 7168    // per-bucket slot stride; mean 6144, sd 78 -> +13 sigma

typedef float vf4 __attribute__((ext_vector_type(4)));   // nt-builtin-compatible

__device__ __forceinline__ int atomAddI(int* p, int v) {
    return __hip_atomic_fetch_add(p, v, __ATOMIC_RELAXED, __HIP_MEMORY_SCOPE_AGENT);
}
__device__ __forceinline__ void atomAddF(float* p, float v) {
    __hip_atomic_fetch_add(p, v, __ATOMIC_RELAXED, __HIP_MEMORY_SCOPE_AGENT);
}

// ---------------- phase A: coarse bucket scatter (packed src|dlow) ----------------
__global__ void __launch_bounds__(256) k_bucket(const int* __restrict__ src,
        const int* __restrict__ dst, int* __restrict__ bcur, unsigned* __restrict__ barr) {
    __shared__ int hcnt[NBK], hbase[NBK], hrank[NBK];
    int tid = threadIdx.x;
    if (tid < NBK) { hcnt[tid] = 0; hrank[tid] = 0; }
    __syncthreads();
    int per = (NE + gridDim.x - 1) / gridDim.x;
    int e0 = blockIdx.x * per, e1 = min(e0 + per, NE);
    for (int e = e0 + tid; e < e1; e += 256)
        atomicAdd(&hcnt[dst[e] >> BSH], 1);
    __syncthreads();
    if (tid < NBK) {
        int c = hcnt[tid];
        hbase[tid] = c ? atomAddI(&bcur[tid], c) : 0;
    }
    __syncthreads();
    for (int e = e0 + tid; e < e1; e += 256) {
        int d = dst[e], s = src[e];
        int b = d >> BSH;
        int r = atomicAdd(&hrank[b], 1);
        __builtin_nontemporal_store(((unsigned)s << BSH) | (unsigned)(d & 511),
                                    &barr[(size_t)b * SLOT + hbase[b] + r]);
    }
}

// ---------------- bucket-count scan ----------------
__global__ void __launch_bounds__(256) k_bscan(const int* __restrict__ bcur,
        int* __restrict__ bstart, int* __restrict__ start) {
    __shared__ int sm[256];
    int t = threadIdx.x;
    int v0 = (t < NBK) ? bcur[t] : 0;
    sm[t] = v0;
    __syncthreads();
    for (int off = 1; off < 256; off <<= 1) {
        int v = (t >= off) ? sm[t - off] : 0;
        __syncthreads();
        sm[t] += v;
        __syncthreads();
    }
    if (t < NBK) bstart[t] = sm[t] - v0;
    if (t == 0) { bstart[NBK] = NE; start[NN] = NE; }
}

// ---------------- phase B: exact CSR within each bucket ----------------
__global__ void __launch_bounds__(256) k_sortb(const int* __restrict__ bcur,
        const int* __restrict__ bstart, const unsigned* __restrict__ barr,
        int* __restrict__ start, int* __restrict__ csr) {
    __shared__ int cnt[512], loc[512], sm[256];
    int t = threadIdx.x;
    int b = blockIdx.x;
    cnt[t] = 0; cnt[t + 256] = 0;
    __syncthreads();
    int count = bcur[b];
    int base  = bstart[b];
    const unsigned* bp = barr + (size_t)b * SLOT;
    for (int i = t; i < count; i += 256)
        atomicAdd(&cnt[__builtin_nontemporal_load(bp + i) & 511], 1);
    __syncthreads();
    int c0 = cnt[2 * t], c1 = cnt[2 * t + 1];
    int s = c0 + c1;
    sm[t] = s;
    __syncthreads();
    for (int off = 1; off < 256; off <<= 1) {
        int v = (t >= off) ? sm[t - off] : 0;
        __syncthreads();
        sm[t] += v;
        __syncthreads();
    }
    int ex = sm[t] - s;
    loc[2 * t] = ex; loc[2 * t + 1] = ex + c0;
    int g0 = b << BSH;
    if (g0 + 2 * t < NN)     start[g0 + 2 * t]     = base + ex;
    if (g0 + 2 * t + 1 < NN) start[g0 + 2 * t + 1] = base + ex + c0;
    __syncthreads();
    for (int i = t; i < count; i += 256) {
        unsigned p = __builtin_nontemporal_load(bp + i);
        int r = atomicAdd(&loc[p & 511], 1);
        __builtin_nontemporal_store((int)(p >> BSH), &csr[base + r]);
    }
}

// ---------------- embedding -> h0 slabs T0[c][n][8] ----------------
__global__ void __launch_bounds__(256) k_embedT(const int* __restrict__ x, const float* __restrict__ emb,
                         float* __restrict__ T0) {
    int tid = blockIdx.x * blockDim.x + threadIdx.x;
    if (tid >= NN * 64) return;
    int c = tid / (NN * 8);
    int r = tid % (NN * 8);
    int n = r >> 3, f = r & 7;
    __builtin_nontemporal_store(emb[(size_t)x[n] * 64 + c * 8 + f], &T0[tid]);
}

// ---------------- chunked aggregate: no-shfl layout, unroll 4, nt streams ----------------
// chunk-per-XCD (c = blockIdx.x & 7): the 3.2 MB slab stays L2-resident because
// csr (nt loads) and agg output (nt stores) bypass/minimize L2 pollution.
__global__ void __launch_bounds__(256) k_agg2(const int* __restrict__ start,
        const int* __restrict__ csr, const float* __restrict__ gT,
        float* __restrict__ aggT) {
    int tid = threadIdx.x;
    int lane = tid & 63, wave = tid >> 6;
    int c  = blockIdx.x & 7;
    int nb = blockIdx.x >> 3;            // 0..781
    int f = lane & 7, nsub = lane >> 3;  // nsub 0..7
    const float* gsl = gT + (size_t)c * NN * 8;
    float* asl = aggT + (size_t)c * NN * 8;

    // streaming L2 warm of this block's slab slice
    float pf = 0.f;
    {
        int i = nb * 256 + tid;
        if (i < NN * 2) {
            float4 v = ((const float4*)gsl)[i];
            pf = v.x * 0.0f;
        }
    }

    int n0 = nb * 128;
    for (int b = 0; b < 4; ++b) {
        int n = n0 + wave * 32 + b * 8 + nsub;
        if (n >= NN) break;
        int s0 = start[n], s1 = start[n + 1];
        float inv = 1.0f / (float)max(s1 - s0, 1);
        float acc = pf, acc2 = 0.f;
        int i = s0;
        for (; i + 4 <= s1; i += 4) {
            int c0 = __builtin_nontemporal_load(csr + i);
            int c1 = __builtin_nontemporal_load(csr + i + 1);
            int c2 = __builtin_nontemporal_load(csr + i + 2);
            int c3 = __builtin_nontemporal_load(csr + i + 3);
            float v0 = gsl[(size_t)c0 * 8 + f];
            float v1 = gsl[(size_t)c1 * 8 + f];
            float v2 = gsl[(size_t)c2 * 8 + f];
            float v3 = gsl[(size_t)c3 * 8 + f];
            acc += v0 + v1;
            acc2 += v2 + v3;
        }
        for (; i < s1; ++i) acc += gsl[(size_t)__builtin_nontemporal_load(csr + i) * 8 + f];
        __builtin_nontemporal_store((acc + acc2) * inv, &asl[(size_t)n * 8 + f]);
    }
}

// ---------------- SAGE linear (+ReLU): one THREAD per node ----------------
__global__ void __launch_bounds__(256) k_lin3(const float* __restrict__ aggT,
        const float* __restrict__ rootT,
        const float* __restrict__ Wl, const float* __restrict__ bl,
        const float* __restrict__ Wr, float* __restrict__ outT) {
    int tid = blockIdx.x * 256 + threadIdx.x;
    int n = tid < NN ? tid : NN - 1;   // clamp; store guarded

    float acc[64];
#pragma unroll
    for (int d = 0; d < 64; ++d) acc[d] = bl[d];

    const float4* ap = (const float4*)(aggT + (size_t)n * 8);
    const float4* rp = (const float4*)(rootT + (size_t)n * 8);
    const size_t cstep = (size_t)NN * 2;   // chunk stride in float4s

    float4 a0 = ap[0], a1 = ap[1], r0 = rp[0], r1 = rp[1];
    for (int c = 0; c < 8; ++c) {
        float av[8] = {a0.x, a0.y, a0.z, a0.w, a1.x, a1.y, a1.z, a1.w};
        float rv[8] = {r0.x, r0.y, r0.z, r0.w, r1.x, r1.y, r1.z, r1.w};
        if (c < 7) {
            size_t off = (size_t)(c + 1) * cstep;
            a0 = ap[off]; a1 = ap[off + 1];
            r0 = rp[off]; r1 = rp[off + 1];
        }
        const float* wlc = Wl + c * 8;   // row d, cols c*8..c*8+7
        const float* wrc = Wr + c * 8;
#pragma unroll
        for (int d = 0; d < 64; ++d) {
#pragma unroll
            for (int k = 0; k < 8; ++k) {
                acc[d] += av[k] * wlc[d * 64 + k];
                acc[d] += rv[k] * wrc[d * 64 + k];
            }
        }
    }

    if (tid < NN) {
#pragma unroll
        for (int c = 0; c < 8; ++c) {
            vf4 o0, o1;
            o0.x = fmaxf(acc[c * 8 + 0], 0.f); o0.y = fmaxf(acc[c * 8 + 1], 0.f);
            o0.z = fmaxf(acc[c * 8 + 2], 0.f); o0.w = fmaxf(acc[c * 8 + 3], 0.f);
            o1.x = fmaxf(acc[c * 8 + 4], 0.f); o1.y = fmaxf(acc[c * 8 + 5], 0.f);
            o1.z = fmaxf(acc[c * 8 + 6], 0.f); o1.w = fmaxf(acc[c * 8 + 7], 0.f);
            vf4* op = (vf4*)(outT + (size_t)c * NN * 8 + (size_t)n * 8);
            __builtin_nontemporal_store(o0, op);
            __builtin_nontemporal_store(o1, op + 1);
        }
    }
}

// ---------------- per-graph mean-pool from h2 slabs (batch sorted) ----------------
__global__ void __launch_bounds__(256) k_pools(const float* __restrict__ hT,
        const int* __restrict__ batch, float* __restrict__ pooled) {
    int lane = threadIdx.x & 63;
    int wave = threadIdx.x >> 6;
    int n0 = blockIdx.x * 256 + wave * 64;
    if (n0 >= NN) return;
    const float* base = hT + (size_t)(lane >> 3) * NN * 8 + (lane & 7);
    int gcur = batch[n0];
    float rsum = 0.f;
    int nend = min(n0 + 64, NN);
    for (int n = n0; n < nend; ++n) {
        float v = base[(size_t)n * 8];
        int g = batch[n];
        if (g != gcur) {
            atomAddF(&pooled[(size_t)gcur * D + lane], rsum);
            rsum = 0.f; gcur = g;
        }
        rsum += v;
    }
    atomAddF(&pooled[(size_t)gcur * D + lane], rsum);
}

// ---------------- readout ----------------
__global__ void __launch_bounds__(256) k_bounds(const int* __restrict__ batch, int* __restrict__ gs) {
    int n = blockIdx.x * blockDim.x + threadIdx.x;
    if (n >= NN) return;
    int b = batch[n];
    if (n == 0) {
        for (int g = 0; g <= b; ++g) gs[g] = 0;
    } else {
        int bp = batch[n - 1];
        for (int g = bp + 1; g <= b; ++g) gs[g] = n;
    }
    if (n == NN - 1) {
        for (int g = b + 1; g <= NG; ++g) gs[g] = NN;
    }
}

__global__ void __launch_bounds__(256) k_out(const int* __restrict__ gs,
        const float* __restrict__ pooled, const float* __restrict__ Wout,
        const float* __restrict__ bout, float* __restrict__ out) {
    int lane = threadIdx.x & 63;
    int wave = threadIdx.x >> 6;
    int g = blockIdx.x * 4 + wave;       // 512 blocks
    int s0 = gs[g], s1 = gs[g + 1];
    float p = pooled[(size_t)g * D + lane] / (float)max(s1 - s0, 1);
    float c0 = p * Wout[lane];
    float c1 = p * Wout[D + lane];
#pragma unroll
    for (int off = 32; off > 0; off >>= 1) {
        c0 += __shfl_down(c0, off, 64);
        c1 += __shfl_down(c1, off, 64);
    }
    if (lane == 0) {
        out[g * C + 0] = c0 + bout[0];
        out[g * C + 1] = c1 + bout[1];
    }
}

extern "C" void kernel_launch(void* const* d_in, const int* in_sizes, int n_in,
                              void* d_out, int out_size, void* d_ws, size_t ws_size,
                              hipStream_t stream) {
    const int*   x     = (const int*)d_in[0];
    const int*   src   = (const int*)d_in[1];
    const int*   dst   = src + NE;
    const int*   batch = (const int*)d_in[2];
    const float* emb   = (const float*)d_in[3];
    const float* W1l   = (const float*)d_in[4];
    const float* b1l   = (const float*)d_in[5];
    const float* W1r   = (const float*)d_in[6];
    const float* W2l   = (const float*)d_in[7];
    const float* b2l   = (const float*)d_in[8];
    const float* W2r   = (const float*)d_in[9];
    const float* Wout  = (const float*)d_in[10];
    const float* bout  = (const float*)d_in[11];
    float* out = (float*)d_out;

    float* T0     = (float*)d_ws;                 // NN*64  h0 -> h1 slabs (in place)
    float* TA     = T0 + (size_t)NN * 64;         // NN*64  agg slabs -> h2 slabs (in place)
    float* pooled = TA + (size_t)NN * 64;         // NG*64
    int* bcur   = (int*)(pooled + (size_t)NG * 64);  // NBK  (contiguous w/ pooled for memset)
    int* bstart = bcur + NBK;                        // NBK+1
    int* startA = bstart + NBK + 1;                  // NN+1
    int* gs     = startA + NN + 1;                   // NG+1
    int* csr    = gs + NG + 1;                       // NE
    unsigned* barr = (unsigned*)(csr + NE);          // NBK*SLOT (~5.6 MB)

    hipMemsetAsync(pooled, 0, ((size_t)NG * 64 + NBK) * sizeof(float), stream);

    k_bucket<<<192, 256, 0, stream>>>(src, dst, bcur, barr);
    k_bscan <<<1, 256, 0, stream>>>(bcur, bstart, startA);
    k_sortb <<<NBK, 256, 0, stream>>>(bcur, bstart, barr, startA, csr);
    k_bounds<<<(NN + 255) / 256, 256, 0, stream>>>(batch, gs);
    k_embedT<<<(NN * 64 + 255) / 256, 256, 0, stream>>>(x, emb, T0);

    // ---- layer 1 ----
    k_agg2<<<((NN + 127) / 128) * 8, 256, 0, stream>>>(startA, csr, T0, TA);
    k_lin3<<<(NN + 255) / 256, 256, 0, stream>>>(TA, T0, W1l, b1l, W1r, T0);
    // ---- layer 2 ----
    k_agg2<<<((NN + 127) / 128) * 8, 256, 0, stream>>>(startA, csr, T0, TA);
    k_lin3<<<(NN + 255) / 256, 256, 0, stream>>>(TA, T0, W2l, b2l, W2r, TA);

    // ---- readout ----
    k_pools<<<(NN + 255) / 256, 256, 0, stream>>>(TA, batch, pooled);
    k_out<<<NG / 4, 256, 0, stream>>>(gs, pooled, Wout, bout, out);
}

// Round 14
// 485.431 us; speedup vs baseline: 1.2028x; 1.2028x over previous
//
#include <hip/hip_runtime.h>

#define NN 100000
#define NE 1200000
#define NG 2048
#define VOCAB 10000
#define D 64
#define C 2

#define NBK 196      // coarse buckets of 512 nodes (dst >> 9)
#define BSH 9
#define SLOT 7168    // per-bucket slot stride; mean 6144, sd 78 -> +13 sigma

typedef float vf4 __attribute__((ext_vector_type(4)));   // nt-builtin-compatible

__device__ __forceinline__ int atomAddI(int* p, int v) {
    return __hip_atomic_fetch_add(p, v, __ATOMIC_RELAXED, __HIP_MEMORY_SCOPE_AGENT);
}
__device__ __forceinline__ void atomAddF(float* p, float v) {
    __hip_atomic_fetch_add(p, v, __ATOMIC_RELAXED, __HIP_MEMORY_SCOPE_AGENT);
}

// ---------------- phase A: coarse bucket scatter (packed src|dlow) ----------------
__global__ void __launch_bounds__(256) k_bucket(const int* __restrict__ src,
        const int* __restrict__ dst, int* __restrict__ bcur, unsigned* __restrict__ barr) {
    __shared__ int hcnt[NBK], hbase[NBK], hrank[NBK];
    int tid = threadIdx.x;
    if (tid < NBK) { hcnt[tid] = 0; hrank[tid] = 0; }
    __syncthreads();
    int per = (NE + gridDim.x - 1) / gridDim.x;
    int e0 = blockIdx.x * per, e1 = min(e0 + per, NE);
    for (int e = e0 + tid; e < e1; e += 256)
        atomicAdd(&hcnt[dst[e] >> BSH], 1);
    __syncthreads();
    if (tid < NBK) {
        int c = hcnt[tid];
        hbase[tid] = c ? atomAddI(&bcur[tid], c) : 0;
    }
    __syncthreads();
    for (int e = e0 + tid; e < e1; e += 256) {
        int d = dst[e], s = src[e];
        int b = d >> BSH;
        int r = atomicAdd(&hrank[b], 1);
        __builtin_nontemporal_store(((unsigned)s << BSH) | (unsigned)(d & 511),
                                    &barr[(size_t)b * SLOT + hbase[b] + r]);
    }
}

// ---------------- bucket-count scan ----------------
__global__ void __launch_bounds__(256) k_bscan(const int* __restrict__ bcur,
        int* __restrict__ bstart, int* __restrict__ start) {
    __shared__ int sm[256];
    int t = threadIdx.x;
    int v0 = (t < NBK) ? bcur[t] : 0;
    sm[t] = v0;
    __syncthreads();
    for (int off = 1; off < 256; off <<= 1) {
        int v = (t >= off) ? sm[t - off] : 0;
        __syncthreads();
        sm[t] += v;
        __syncthreads();
    }
    if (t < NBK) bstart[t] = sm[t] - v0;
    if (t == 0) { bstart[NBK] = NE; start[NN] = NE; }
}

// ---------------- phase B: exact CSR within each bucket ----------------
__global__ void __launch_bounds__(256) k_sortb(const int* __restrict__ bcur,
        const int* __restrict__ bstart, const unsigned* __restrict__ barr,
        int* __restrict__ start, int* __restrict__ csr) {
    __shared__ int cnt[512], loc[512], sm[256];
    int t = threadIdx.x;
    int b = blockIdx.x;
    cnt[t] = 0; cnt[t + 256] = 0;
    __syncthreads();
    int count = bcur[b];
    int base  = bstart[b];
    const unsigned* bp = barr + (size_t)b * SLOT;
    for (int i = t; i < count; i += 256)
        atomicAdd(&cnt[bp[i] & 511], 1);
    __syncthreads();
    int c0 = cnt[2 * t], c1 = cnt[2 * t + 1];
    int s = c0 + c1;
    sm[t] = s;
    __syncthreads();
    for (int off = 1; off < 256; off <<= 1) {
        int v = (t >= off) ? sm[t - off] : 0;
        __syncthreads();
        sm[t] += v;
        __syncthreads();
    }
    int ex = sm[t] - s;
    loc[2 * t] = ex; loc[2 * t + 1] = ex + c0;
    int g0 = b << BSH;
    if (g0 + 2 * t < NN)     start[g0 + 2 * t]     = base + ex;
    if (g0 + 2 * t + 1 < NN) start[g0 + 2 * t + 1] = base + ex + c0;
    __syncthreads();
    for (int i = t; i < count; i += 256) {
        unsigned p = bp[i];
        int r = atomicAdd(&loc[p & 511], 1);
        __builtin_nontemporal_store((int)(p >> BSH), &csr[base + r]);
    }
}

// ---------------- embedding -> h0 slabs T0[c][n][8] ----------------
__global__ void __launch_bounds__(256) k_embedT(const int* __restrict__ x, const float* __restrict__ emb,
                         float* __restrict__ T0) {
    int tid = blockIdx.x * blockDim.x + threadIdx.x;
    if (tid >= NN * 64) return;
    int c = tid / (NN * 8);
    int r = tid % (NN * 8);
    int n = r >> 3, f = r & 7;
    __builtin_nontemporal_store(emb[(size_t)x[n] * 64 + c * 8 + f], &T0[tid]);
}

// ---------------- chunked aggregate: cached loads, nt store ----------------
// chunk-per-XCD (c = blockIdx.x & 7). csr/slab loads CACHED (csr lines have
// ~128-way intra-wave reuse; slab is the L2-resident working set). agg output
// nt-stored: single-use downstream, avoids write-allocate fetch (~25.6 MB).
__global__ void __launch_bounds__(256) k_agg2(const int* __restrict__ start,
        const int* __restrict__ csr, const float* __restrict__ gT,
        float* __restrict__ aggT) {
    int tid = threadIdx.x;
    int lane = tid & 63, wave = tid >> 6;
    int c  = blockIdx.x & 7;
    int nb = blockIdx.x >> 3;            // 0..781
    int f = lane & 7, nsub = lane >> 3;  // nsub 0..7
    const float* gsl = gT + (size_t)c * NN * 8;
    float* asl = aggT + (size_t)c * NN * 8;

    // streaming L2 warm of this block's slab slice
    float pf = 0.f;
    {
        int i = nb * 256 + tid;
        if (i < NN * 2) {
            float4 v = ((const float4*)gsl)[i];
            pf = v.x * 0.0f;
        }
    }

    int n0 = nb * 128;
    for (int b = 0; b < 4; ++b) {
        int n = n0 + wave * 32 + b * 8 + nsub;
        if (n >= NN) break;
        int s0 = start[n], s1 = start[n + 1];
        float inv = 1.0f / (float)max(s1 - s0, 1);
        float acc = pf, acc2 = 0.f;
        int i = s0;
        for (; i + 4 <= s1; i += 4) {
            int c0 = csr[i], c1 = csr[i + 1], c2 = csr[i + 2], c3 = csr[i + 3];
            float v0 = gsl[(size_t)c0 * 8 + f];
            float v1 = gsl[(size_t)c1 * 8 + f];
            float v2 = gsl[(size_t)c2 * 8 + f];
            float v3 = gsl[(size_t)c3 * 8 + f];
            acc += v0 + v1;
            acc2 += v2 + v3;
        }
        for (; i < s1; ++i) acc += gsl[(size_t)csr[i] * 8 + f];
        __builtin_nontemporal_store((acc + acc2) * inv, &asl[(size_t)n * 8 + f]);
    }
}

// ---------------- SAGE linear (+ReLU): one THREAD per node ----------------
__global__ void __launch_bounds__(256) k_lin3(const float* __restrict__ aggT,
        const float* __restrict__ rootT,
        const float* __restrict__ Wl, const float* __restrict__ bl,
        const float* __restrict__ Wr, float* __restrict__ outT) {
    int tid = blockIdx.x * 256 + threadIdx.x;
    int n = tid < NN ? tid : NN - 1;   // clamp; store guarded

    float acc[64];
#pragma unroll
    for (int d = 0; d < 64; ++d) acc[d] = bl[d];

    const float4* ap = (const float4*)(aggT + (size_t)n * 8);
    const float4* rp = (const float4*)(rootT + (size_t)n * 8);
    const size_t cstep = (size_t)NN * 2;   // chunk stride in float4s

    float4 a0 = ap[0], a1 = ap[1], r0 = rp[0], r1 = rp[1];
    for (int c = 0; c < 8; ++c) {
        float av[8] = {a0.x, a0.y, a0.z, a0.w, a1.x, a1.y, a1.z, a1.w};
        float rv[8] = {r0.x, r0.y, r0.z, r0.w, r1.x, r1.y, r1.z, r1.w};
        if (c < 7) {
            size_t off = (size_t)(c + 1) * cstep;
            a0 = ap[off]; a1 = ap[off + 1];
            r0 = rp[off]; r1 = rp[off + 1];
        }
        const float* wlc = Wl + c * 8;   // row d, cols c*8..c*8+7
        const float* wrc = Wr + c * 8;
#pragma unroll
        for (int d = 0; d < 64; ++d) {
#pragma unroll
            for (int k = 0; k < 8; ++k) {
                acc[d] += av[k] * wlc[d * 64 + k];
                acc[d] += rv[k] * wrc[d * 64 + k];
            }
        }
    }

    if (tid < NN) {
#pragma unroll
        for (int c = 0; c < 8; ++c) {
            vf4 o0, o1;
            o0.x = fmaxf(acc[c * 8 + 0], 0.f); o0.y = fmaxf(acc[c * 8 + 1], 0.f);
            o0.z = fmaxf(acc[c * 8 + 2], 0.f); o0.w = fmaxf(acc[c * 8 + 3], 0.f);
            o1.x = fmaxf(acc[c * 8 + 4], 0.f); o1.y = fmaxf(acc[c * 8 + 5], 0.f);
            o1.z = fmaxf(acc[c * 8 + 6], 0.f); o1.w = fmaxf(acc[c * 8 + 7], 0.f);
            vf4* op = (vf4*)(outT + (size_t)c * NN * 8 + (size_t)n * 8);
            __builtin_nontemporal_store(o0, op);
            __builtin_nontemporal_store(o1, op + 1);
        }
    }
}

// ---------------- per-graph mean-pool from h2 slabs (batch sorted) ----------------
__global__ void __launch_bounds__(256) k_pools(const float* __restrict__ hT,
        const int* __restrict__ batch, float* __restrict__ pooled) {
    int lane = threadIdx.x & 63;
    int wave = threadIdx.x >> 6;
    int n0 = blockIdx.x * 256 + wave * 64;
    if (n0 >= NN) return;
    const float* base = hT + (size_t)(lane >> 3) * NN * 8 + (lane & 7);
    int gcur = batch[n0];
    float rsum = 0.f;
    int nend = min(n0 + 64, NN);
    for (int n = n0; n < nend; ++n) {
        float v = base[(size_t)n * 8];
        int g = batch[n];
        if (g != gcur) {
            atomAddF(&pooled[(size_t)gcur * D + lane], rsum);
            rsum = 0.f; gcur = g;
        }
        rsum += v;
    }
    atomAddF(&pooled[(size_t)gcur * D + lane], rsum);
}

// ---------------- readout ----------------
__global__ void __launch_bounds__(256) k_bounds(const int* __restrict__ batch, int* __restrict__ gs) {
    int n = blockIdx.x * blockDim.x + threadIdx.x;
    if (n >= NN) return;
    int b = batch[n];
    if (n == 0) {
        for (int g = 0; g <= b; ++g) gs[g] = 0;
    } else {
        int bp = batch[n - 1];
        for (int g = bp + 1; g <= b; ++g) gs[g] = n;
    }
    if (n == NN - 1) {
        for (int g = b + 1; g <= NG; ++g) gs[g] = NN;
    }
}

__global__ void __launch_bounds__(256) k_out(const int* __restrict__ gs,
        const float* __restrict__ pooled, const float* __restrict__ Wout,
        const float* __restrict__ bout, float* __restrict__ out) {
    int lane = threadIdx.x & 63;
    int wave = threadIdx.x >> 6;
    int g = blockIdx.x * 4 + wave;       // 512 blocks
    int s0 = gs[g], s1 = gs[g + 1];
    float p = pooled[(size_t)g * D + lane] / (float)max(s1 - s0, 1);
    float c0 = p * Wout[lane];
    float c1 = p * Wout[D + lane];
#pragma unroll
    for (int off = 32; off > 0; off >>= 1) {
        c0 += __shfl_down(c0, off, 64);
        c1 += __shfl_down(c1, off, 64);
    }
    if (lane == 0) {
        out[g * C + 0] = c0 + bout[0];
        out[g * C + 1] = c1 + bout[1];
    }
}

extern "C" void kernel_launch(void* const* d_in, const int* in_sizes, int n_in,
                              void* d_out, int out_size, void* d_ws, size_t ws_size,
                              hipStream_t stream) {
    const int*   x     = (const int*)d_in[0];
    const int*   src   = (const int*)d_in[1];
    const int*   dst   = src + NE;
    const int*   batch = (const int*)d_in[2];
    const float* emb   = (const float*)d_in[3];
    const float* W1l   = (const float*)d_in[4];
    const float* b1l   = (const float*)d_in[5];
    const float* W1r   = (const float*)d_in[6];
    const float* W2l   = (const float*)d_in[7];
    const float* b2l   = (const float*)d_in[8];
    const float* W2r   = (const float*)d_in[9];
    const float* Wout  = (const float*)d_in[10];
    const float* bout  = (const float*)d_in[11];
    float* out = (float*)d_out;

    float* T0     = (float*)d_ws;                 // NN*64  h0 -> h1 slabs (in place)
    float* TA     = T0 + (size_t)NN * 64;         // NN*64  agg slabs -> h2 slabs (in place)
    float* pooled = TA + (size_t)NN * 64;         // NG*64
    int* bcur   = (int*)(pooled + (size_t)NG * 64);  // NBK  (contiguous w/ pooled for memset)
    int* bstart = bcur + NBK;                        // NBK+1
    int* startA = bstart + NBK + 1;                  // NN+1
    int* gs     = startA + NN + 1;                   // NG+1
    int* csr    = gs + NG + 1;                       // NE
    unsigned* barr = (unsigned*)(csr + NE);          // NBK*SLOT (~5.6 MB)

    hipMemsetAsync(pooled, 0, ((size_t)NG * 64 + NBK) * sizeof(float), stream);

    k_bucket<<<192, 256, 0, stream>>>(src, dst, bcur, barr);
    k_bscan <<<1, 256, 0, stream>>>(bcur, bstart, startA);
    k_sortb <<<NBK, 256, 0, stream>>>(bcur, bstart, barr, startA, csr);
    k_bounds<<<(NN + 255) / 256, 256, 0, stream>>>(batch, gs);
    k_embedT<<<(NN * 64 + 255) / 256, 256, 0, stream>>>(x, emb, T0);

    // ---- layer 1 ----
    k_agg2<<<((NN + 127) / 128) * 8, 256, 0, stream>>>(startA, csr, T0, TA);
    k_lin3<<<(NN + 255) / 256, 256, 0, stream>>>(TA, T0, W1l, b1l, W1r, T0);
    // ---- layer 2 ----
    k_agg2<<<((NN + 127) / 128) * 8, 256, 0, stream>>>(startA, csr, T0, TA);
    k_lin3<<<(NN + 255) / 256, 256, 0, stream>>>(TA, T0, W2l, b2l, W2r, TA);

    // ---- readout ----
    k_pools<<<(NN + 255) / 256, 256, 0, stream>>>(TA, batch, pooled);
    k_out<<<NG / 4, 256, 0, stream>>>(gs, pooled, Wout, bout, out);
}

// Round 15
// 443.125 us; speedup vs baseline: 1.3177x; 1.0955x over previous
//
#include <hip/hip_runtime.h>

#define NN 100000
#define NE 1200000
#define NG 2048
#define VOCAB 10000
#define D 64
#define C 2

#define NBK 196      // coarse buckets of 512 nodes (dst >> 9)
#define BSH 9
#define SLOT 7168    // per-bucket slot stride; mean 6144, sd 78 -> +13 sigma

__device__ __forceinline__ int atomAddI(int* p, int v) {
    return __hip_atomic_fetch_add(p, v, __ATOMIC_RELAXED, __HIP_MEMORY_SCOPE_AGENT);
}
__device__ __forceinline__ void atomAddF(float* p, float v) {
    __hip_atomic_fetch_add(p, v, __ATOMIC_RELAXED, __HIP_MEMORY_SCOPE_AGENT);
}

// ---------------- phase A: coarse bucket scatter (packed src|dlow) ----------------
__global__ void __launch_bounds__(256) k_bucket(const int* __restrict__ src,
        const int* __restrict__ dst, int* __restrict__ bcur, unsigned* __restrict__ barr) {
    __shared__ int hcnt[NBK], hbase[NBK], hrank[NBK];
    int tid = threadIdx.x;
    if (tid < NBK) { hcnt[tid] = 0; hrank[tid] = 0; }
    __syncthreads();
    int per = (NE + gridDim.x - 1) / gridDim.x;
    int e0 = blockIdx.x * per, e1 = min(e0 + per, NE);
    for (int e = e0 + tid; e < e1; e += 256)
        atomicAdd(&hcnt[dst[e] >> BSH], 1);
    __syncthreads();
    if (tid < NBK) {
        int c = hcnt[tid];
        hbase[tid] = c ? atomAddI(&bcur[tid], c) : 0;
    }
    __syncthreads();
    for (int e = e0 + tid; e < e1; e += 256) {
        int d = dst[e], s = src[e];
        int b = d >> BSH;
        int r = atomicAdd(&hrank[b], 1);
        barr[(size_t)b * SLOT + hbase[b] + r] = ((unsigned)s << BSH) | (unsigned)(d & 511);
    }
}

// ---------------- bucket-count scan ----------------
__global__ void __launch_bounds__(256) k_bscan(const int* __restrict__ bcur,
        int* __restrict__ bstart, int* __restrict__ start) {
    __shared__ int sm[256];
    int t = threadIdx.x;
    int v0 = (t < NBK) ? bcur[t] : 0;
    sm[t] = v0;
    __syncthreads();
    for (int off = 1; off < 256; off <<= 1) {
        int v = (t >= off) ? sm[t - off] : 0;
        __syncthreads();
        sm[t] += v;
        __syncthreads();
    }
    if (t < NBK) bstart[t] = sm[t] - v0;
    if (t == 0) { bstart[NBK] = NE; start[NN] = NE; }
}

// ---------------- phase B: exact CSR within each bucket ----------------
__global__ void __launch_bounds__(256) k_sortb(const int* __restrict__ bcur,
        const int* __restrict__ bstart, const unsigned* __restrict__ barr,
        int* __restrict__ start, int* __restrict__ csr) {
    __shared__ int cnt[512], loc[512], sm[256];
    int t = threadIdx.x;
    int b = blockIdx.x;
    cnt[t] = 0; cnt[t + 256] = 0;
    __syncthreads();
    int count = bcur[b];
    int base  = bstart[b];
    const unsigned* bp = barr + (size_t)b * SLOT;
    for (int i = t; i < count; i += 256)
        atomicAdd(&cnt[bp[i] & 511], 1);
    __syncthreads();
    int c0 = cnt[2 * t], c1 = cnt[2 * t + 1];
    int s = c0 + c1;
    sm[t] = s;
    __syncthreads();
    for (int off = 1; off < 256; off <<= 1) {
        int v = (t >= off) ? sm[t - off] : 0;
        __syncthreads();
        sm[t] += v;
        __syncthreads();
    }
    int ex = sm[t] - s;
    loc[2 * t] = ex; loc[2 * t + 1] = ex + c0;
    int g0 = b << BSH;
    if (g0 + 2 * t < NN)     start[g0 + 2 * t]     = base + ex;
    if (g0 + 2 * t + 1 < NN) start[g0 + 2 * t + 1] = base + ex + c0;
    __syncthreads();
    for (int i = t; i < count; i += 256) {
        unsigned p = bp[i];
        int r = atomicAdd(&loc[p & 511], 1);
        csr[base + r] = (int)(p >> BSH);
    }
}

// ---------------- embedding -> h0 slabs T0[c][n][8] ----------------
__global__ void __launch_bounds__(256) k_embedT(const int* __restrict__ x, const float* __restrict__ emb,
                         float* __restrict__ T0) {
    int tid = blockIdx.x * blockDim.x + threadIdx.x;
    if (tid >= NN * 64) return;
    int c = tid / (NN * 8);
    int r = tid % (NN * 8);
    int n = r >> 3, f = r & 7;
    T0[tid] = emb[(size_t)x[n] * 64 + c * 8 + f];
}

// ---------------- chunked aggregate: dual-node interleave (8 gathers in flight) ----
// chunk-per-XCD (c = blockIdx.x & 7); lane = nsub(8 nodes) x f(8). Each lane
// accumulates feature f of TWO nodes concurrently (independent edge streams)
// -> 8 outstanding gather chains per lane. 1/deg folded into the store.
__global__ void __launch_bounds__(256) k_agg2(const int* __restrict__ start,
        const int* __restrict__ csr, const float* __restrict__ gT,
        float* __restrict__ aggT) {
    int tid = threadIdx.x;
    int lane = tid & 63, wave = tid >> 6;
    int c  = blockIdx.x & 7;
    int nb = blockIdx.x >> 3;            // 0..781
    int f = lane & 7, nsub = lane >> 3;  // nsub 0..7
    const float* gsl = gT + (size_t)c * NN * 8;
    float* asl = aggT + (size_t)c * NN * 8;

    // streaming L2 warm of this block's slab slice
    float pf = 0.f;
    {
        int i = nb * 256 + tid;
        if (i < NN * 2) {
            float4 v = ((const float4*)gsl)[i];
            pf = v.x * 0.0f;
        }
    }

    int n0 = nb * 128 + wave * 32 + nsub;
    for (int b = 0; b < 2; ++b) {
        int nA = n0 + b * 16;
        int nB = nA + 8;
        bool okA = nA < NN, okB = nB < NN;
        int cA = okA ? nA : 0, cB = okB ? nB : 0;
        int sA0 = start[cA], sA1 = okA ? start[cA + 1] : sA0;
        int sB0 = start[cB], sB1 = okB ? start[cB + 1] : sB0;
        float aA0 = pf, aA1 = 0.f, aB0 = 0.f, aB1 = 0.f;
        int iA = sA0, iB = sB0;
        // merged main loop: 8 independent gathers in flight
        while (iA + 4 <= sA1 && iB + 4 <= sB1) {
            int a0 = csr[iA], a1 = csr[iA + 1], a2 = csr[iA + 2], a3 = csr[iA + 3];
            int b0 = csr[iB], b1 = csr[iB + 1], b2 = csr[iB + 2], b3 = csr[iB + 3];
            float vA0 = gsl[(size_t)a0 * 8 + f];
            float vA1 = gsl[(size_t)a1 * 8 + f];
            float vA2 = gsl[(size_t)a2 * 8 + f];
            float vA3 = gsl[(size_t)a3 * 8 + f];
            float vB0 = gsl[(size_t)b0 * 8 + f];
            float vB1 = gsl[(size_t)b1 * 8 + f];
            float vB2 = gsl[(size_t)b2 * 8 + f];
            float vB3 = gsl[(size_t)b3 * 8 + f];
            aA0 += vA0 + vA1; aA1 += vA2 + vA3;
            aB0 += vB0 + vB1; aB1 += vB2 + vB3;
            iA += 4; iB += 4;
        }
        // tails (unroll-4 then scalar)
        for (; iA + 4 <= sA1; iA += 4) {
            int a0 = csr[iA], a1 = csr[iA + 1], a2 = csr[iA + 2], a3 = csr[iA + 3];
            aA0 += gsl[(size_t)a0 * 8 + f] + gsl[(size_t)a1 * 8 + f];
            aA1 += gsl[(size_t)a2 * 8 + f] + gsl[(size_t)a3 * 8 + f];
        }
        for (; iB + 4 <= sB1; iB += 4) {
            int b0 = csr[iB], b1 = csr[iB + 1], b2 = csr[iB + 2], b3 = csr[iB + 3];
            aB0 += gsl[(size_t)b0 * 8 + f] + gsl[(size_t)b1 * 8 + f];
            aB1 += gsl[(size_t)b2 * 8 + f] + gsl[(size_t)b3 * 8 + f];
        }
        for (; iA < sA1; ++iA) aA0 += gsl[(size_t)csr[iA] * 8 + f];
        for (; iB < sB1; ++iB) aB0 += gsl[(size_t)csr[iB] * 8 + f];
        if (okA) {
            float invA = 1.0f / (float)max(sA1 - sA0, 1);
            asl[(size_t)nA * 8 + f] = (aA0 + aA1) * invA;
        }
        if (okB) {
            float invB = 1.0f / (float)max(sB1 - sB0, 1);
            asl[(size_t)nB * 8 + f] = (aB0 + aB1) * invB;
        }
    }
}

// ---------------- SAGE linear (+ReLU): one THREAD per node ----------------
__global__ void __launch_bounds__(256) k_lin3(const float* __restrict__ aggT,
        const float* __restrict__ rootT,
        const float* __restrict__ Wl, const float* __restrict__ bl,
        const float* __restrict__ Wr, float* __restrict__ outT) {
    int tid = blockIdx.x * 256 + threadIdx.x;
    int n = tid < NN ? tid : NN - 1;   // clamp; store guarded

    float acc[64];
#pragma unroll
    for (int d = 0; d < 64; ++d) acc[d] = bl[d];

    const float4* ap = (const float4*)(aggT + (size_t)n * 8);
    const float4* rp = (const float4*)(rootT + (size_t)n * 8);
    const size_t cstep = (size_t)NN * 2;   // chunk stride in float4s

    float4 a0 = ap[0], a1 = ap[1], r0 = rp[0], r1 = rp[1];
    for (int c = 0; c < 8; ++c) {
        float av[8] = {a0.x, a0.y, a0.z, a0.w, a1.x, a1.y, a1.z, a1.w};
        float rv[8] = {r0.x, r0.y, r0.z, r0.w, r1.x, r1.y, r1.z, r1.w};
        if (c < 7) {
            size_t off = (size_t)(c + 1) * cstep;
            a0 = ap[off]; a1 = ap[off + 1];
            r0 = rp[off]; r1 = rp[off + 1];
        }
        const float* wlc = Wl + c * 8;   // row d, cols c*8..c*8+7
        const float* wrc = Wr + c * 8;
#pragma unroll
        for (int d = 0; d < 64; ++d) {
#pragma unroll
            for (int k = 0; k < 8; ++k) {
                acc[d] += av[k] * wlc[d * 64 + k];
                acc[d] += rv[k] * wrc[d * 64 + k];
            }
        }
    }

    if (tid < NN) {
#pragma unroll
        for (int c = 0; c < 8; ++c) {
            float4 o0, o1;
            o0.x = fmaxf(acc[c * 8 + 0], 0.f); o0.y = fmaxf(acc[c * 8 + 1], 0.f);
            o0.z = fmaxf(acc[c * 8 + 2], 0.f); o0.w = fmaxf(acc[c * 8 + 3], 0.f);
            o1.x = fmaxf(acc[c * 8 + 4], 0.f); o1.y = fmaxf(acc[c * 8 + 5], 0.f);
            o1.z = fmaxf(acc[c * 8 + 6], 0.f); o1.w = fmaxf(acc[c * 8 + 7], 0.f);
            float4* op = (float4*)(outT + (size_t)c * NN * 8 + (size_t)n * 8);
            op[0] = o0; op[1] = o1;
        }
    }
}

// ---------------- per-graph mean-pool from h2 slabs (batch sorted) ----------------
__global__ void __launch_bounds__(256) k_pools(const float* __restrict__ hT,
        const int* __restrict__ batch, float* __restrict__ pooled) {
    int lane = threadIdx.x & 63;
    int wave = threadIdx.x >> 6;
    int n0 = blockIdx.x * 256 + wave * 64;
    if (n0 >= NN) return;
    const float* base = hT + (size_t)(lane >> 3) * NN * 8 + (lane & 7);
    int gcur = batch[n0];
    float rsum = 0.f;
    int nend = min(n0 + 64, NN);
    for (int n = n0; n < nend; ++n) {
        float v = base[(size_t)n * 8];
        int g = batch[n];
        if (g != gcur) {
            atomAddF(&pooled[(size_t)gcur * D + lane], rsum);
            rsum = 0.f; gcur = g;
        }
        rsum += v;
    }
    atomAddF(&pooled[(size_t)gcur * D + lane], rsum);
}

// ---------------- readout ----------------
__global__ void __launch_bounds__(256) k_bounds(const int* __restrict__ batch, int* __restrict__ gs) {
    int n = blockIdx.x * blockDim.x + threadIdx.x;
    if (n >= NN) return;
    int b = batch[n];
    if (n == 0) {
        for (int g = 0; g <= b; ++g) gs[g] = 0;
    } else {
        int bp = batch[n - 1];
        for (int g = bp + 1; g <= b; ++g) gs[g] = n;
    }
    if (n == NN - 1) {
        for (int g = b + 1; g <= NG; ++g) gs[g] = NN;
    }
}

__global__ void __launch_bounds__(256) k_out(const int* __restrict__ gs,
        const float* __restrict__ pooled, const float* __restrict__ Wout,
        const float* __restrict__ bout, float* __restrict__ out) {
    int lane = threadIdx.x & 63;
    int wave = threadIdx.x >> 6;
    int g = blockIdx.x * 4 + wave;       // 512 blocks
    int s0 = gs[g], s1 = gs[g + 1];
    float p = pooled[(size_t)g * D + lane] / (float)max(s1 - s0, 1);
    float c0 = p * Wout[lane];
    float c1 = p * Wout[D + lane];
#pragma unroll
    for (int off = 32; off > 0; off >>= 1) {
        c0 += __shfl_down(c0, off, 64);
        c1 += __shfl_down(c1, off, 64);
    }
    if (lane == 0) {
        out[g * C + 0] = c0 + bout[0];
        out[g * C + 1] = c1 + bout[1];
    }
}

extern "C" void kernel_launch(void* const* d_in, const int* in_sizes, int n_in,
                              void* d_out, int out_size, void* d_ws, size_t ws_size,
                              hipStream_t stream) {
    const int*   x     = (const int*)d_in[0];
    const int*   src   = (const int*)d_in[1];
    const int*   dst   = src + NE;
    const int*   batch = (const int*)d_in[2];
    const float* emb   = (const float*)d_in[3];
    const float* W1l   = (const float*)d_in[4];
    const float* b1l   = (const float*)d_in[5];
    const float* W1r   = (const float*)d_in[6];
    const float* W2l   = (const float*)d_in[7];
    const float* b2l   = (const float*)d_in[8];
    const float* W2r   = (const float*)d_in[9];
    const float* Wout  = (const float*)d_in[10];
    const float* bout  = (const float*)d_in[11];
    float* out = (float*)d_out;

    float* T0     = (float*)d_ws;                 // NN*64  h0 -> h1 slabs (in place)
    float* TA     = T0 + (size_t)NN * 64;         // NN*64  agg slabs -> h2 slabs (in place)
    float* pooled = TA + (size_t)NN * 64;         // NG*64
    int* bcur   = (int*)(pooled + (size_t)NG * 64);  // NBK  (contiguous w/ pooled for memset)
    int* bstart = bcur + NBK;                        // NBK+1
    int* startA = bstart + NBK + 1;                  // NN+1
    int* gs     = startA + NN + 1;                   // NG+1
    int* csr    = gs + NG + 1;                       // NE
    unsigned* barr = (unsigned*)(csr + NE);          // NBK*SLOT (~5.6 MB)

    hipMemsetAsync(pooled, 0, ((size_t)NG * 64 + NBK) * sizeof(float), stream);

    k_bucket<<<192, 256, 0, stream>>>(src, dst, bcur, barr);
    k_bscan <<<1, 256, 0, stream>>>(bcur, bstart, startA);
    k_sortb <<<NBK, 256, 0, stream>>>(bcur, bstart, barr, startA, csr);
    k_bounds<<<(NN + 255) / 256, 256, 0, stream>>>(batch, gs);
    k_embedT<<<(NN * 64 + 255) / 256, 256, 0, stream>>>(x, emb, T0);

    // ---- layer 1 ----
    k_agg2<<<((NN + 127) / 128) * 8, 256, 0, stream>>>(startA, csr, T0, TA);
    k_lin3<<<(NN + 255) / 256, 256, 0, stream>>>(TA, T0, W1l, b1l, W1r, T0);
    // ---- layer 2 ----
    k_agg2<<<((NN + 127) / 128) * 8, 256, 0, stream>>>(startA, csr, T0, TA);
    k_lin3<<<(NN + 255) / 256, 256, 0, stream>>>(TA, T0, W2l, b2l, W2r, TA);

    // ---- readout ----
    k_pools<<<(NN + 255) / 256, 256, 0, stream>>>(TA, batch, pooled);
    k_out<<<NG / 4, 256, 0, stream>>>(gs, pooled, Wout, bout, out);
}

// Round 16
// 413.797 us; speedup vs baseline: 1.4111x; 1.0709x over previous
//
#include <hip/hip_runtime.h>

#define NN 100000
#define NE 1200000
#define NG 2048
#define VOCAB 10000
#define D 64
#define C 2

#define NBK 196      // coarse buckets of 512 nodes (dst >> 9)
#define BSH 9
#define SLOT 7168    // per-bucket slot stride; mean 6144, sd 78 -> +13 sigma

__device__ __forceinline__ int atomAddI(int* p, int v) {
    return __hip_atomic_fetch_add(p, v, __ATOMIC_RELAXED, __HIP_MEMORY_SCOPE_AGENT);
}
__device__ __forceinline__ void atomAddF(float* p, float v) {
    __hip_atomic_fetch_add(p, v, __ATOMIC_RELAXED, __HIP_MEMORY_SCOPE_AGENT);
}

// ---------------- phase A: coarse bucket scatter (packed src|dlow) ----------------
__global__ void __launch_bounds__(256) k_bucket(const int* __restrict__ src,
        const int* __restrict__ dst, int* __restrict__ bcur, unsigned* __restrict__ barr) {
    __shared__ int hcnt[NBK], hbase[NBK], hrank[NBK];
    int tid = threadIdx.x;
    if (tid < NBK) { hcnt[tid] = 0; hrank[tid] = 0; }
    __syncthreads();
    int per = (NE + gridDim.x - 1) / gridDim.x;
    int e0 = blockIdx.x * per, e1 = min(e0 + per, NE);
    for (int e = e0 + tid; e < e1; e += 256)
        atomicAdd(&hcnt[dst[e] >> BSH], 1);
    __syncthreads();
    if (tid < NBK) {
        int c = hcnt[tid];
        hbase[tid] = c ? atomAddI(&bcur[tid], c) : 0;
    }
    __syncthreads();
    for (int e = e0 + tid; e < e1; e += 256) {
        int d = dst[e], s = src[e];
        int b = d >> BSH;
        int r = atomicAdd(&hrank[b], 1);
        barr[(size_t)b * SLOT + hbase[b] + r] = ((unsigned)s << BSH) | (unsigned)(d & 511);
    }
}

// ---------------- bucket-count scan ----------------
__global__ void __launch_bounds__(256) k_bscan(const int* __restrict__ bcur,
        int* __restrict__ bstart, int* __restrict__ start) {
    __shared__ int sm[256];
    int t = threadIdx.x;
    int v0 = (t < NBK) ? bcur[t] : 0;
    sm[t] = v0;
    __syncthreads();
    for (int off = 1; off < 256; off <<= 1) {
        int v = (t >= off) ? sm[t - off] : 0;
        __syncthreads();
        sm[t] += v;
        __syncthreads();
    }
    if (t < NBK) bstart[t] = sm[t] - v0;
    if (t == 0) { bstart[NBK] = NE; start[NN] = NE; }
}

// ---------------- phase B: exact CSR within each bucket ----------------
__global__ void __launch_bounds__(256) k_sortb(const int* __restrict__ bcur,
        const int* __restrict__ bstart, const unsigned* __restrict__ barr,
        int* __restrict__ start, int* __restrict__ csr) {
    __shared__ int cnt[512], loc[512], sm[256];
    int t = threadIdx.x;
    int b = blockIdx.x;
    cnt[t] = 0; cnt[t + 256] = 0;
    __syncthreads();
    int count = bcur[b];
    int base  = bstart[b];
    const unsigned* bp = barr + (size_t)b * SLOT;
    for (int i = t; i < count; i += 256)
        atomicAdd(&cnt[bp[i] & 511], 1);
    __syncthreads();
    int c0 = cnt[2 * t], c1 = cnt[2 * t + 1];
    int s = c0 + c1;
    sm[t] = s;
    __syncthreads();
    for (int off = 1; off < 256; off <<= 1) {
        int v = (t >= off) ? sm[t - off] : 0;
        __syncthreads();
        sm[t] += v;
        __syncthreads();
    }
    int ex = sm[t] - s;
    loc[2 * t] = ex; loc[2 * t + 1] = ex + c0;
    int g0 = b << BSH;
    if (g0 + 2 * t < NN)     start[g0 + 2 * t]     = base + ex;
    if (g0 + 2 * t + 1 < NN) start[g0 + 2 * t + 1] = base + ex + c0;
    __syncthreads();
    for (int i = t; i < count; i += 256) {
        unsigned p = bp[i];
        int r = atomicAdd(&loc[p & 511], 1);
        csr[base + r] = (int)(p >> BSH);
    }
}

// ---------------- embedding -> h0 slabs T0[c][n][8] ----------------
__global__ void __launch_bounds__(256) k_embedT(const int* __restrict__ x, const float* __restrict__ emb,
                         float* __restrict__ T0) {
    int tid = blockIdx.x * blockDim.x + threadIdx.x;
    if (tid >= NN * 64) return;
    int c = tid / (NN * 8);
    int r = tid % (NN * 8);
    int n = r >> 3, f = r & 7;
    T0[tid] = emb[(size_t)x[n] * 64 + c * 8 + f];
}

// ---------------- chunked aggregate: float2 lanes (16 edges / gather instr) ----
// chunk-per-XCD (c = blockIdx.x & 7). lane = nsub(16 nodes) x f2(4 float2):
// 4 lanes cover a 32B row -> one wave gather instruction covers 16 edges
// (vs 8 with float lanes). No cross-lane reduction. 1/deg folded into store.
__global__ void __launch_bounds__(256) k_agg2(const int* __restrict__ start,
        const int* __restrict__ csr, const float* __restrict__ gT,
        float* __restrict__ aggT) {
    int tid = threadIdx.x;
    int lane = tid & 63, wave = tid >> 6;
    int c  = blockIdx.x & 7;
    int nb = blockIdx.x >> 3;            // 0..781
    int f2 = lane & 3, nsub = lane >> 2; // nsub 0..15
    const float2* gsl2 = (const float2*)(gT + (size_t)c * NN * 8);
    float2* asl2 = (float2*)(aggT + (size_t)c * NN * 8);

    // streaming L2 warm of this block's slab slice
    float pf = 0.f;
    {
        int i = nb * 256 + tid;
        if (i < NN * 2) {
            float4 v = ((const float4*)gsl2)[i];
            pf = v.x * 0.0f;
        }
    }

    int nbase = nb * 128 + wave * 16 + nsub;
    for (int b = 0; b < 2; ++b) {
        int n = nbase + b * 64;
        if (n >= NN) break;
        int s0 = start[n], s1 = start[n + 1];
        float inv = 1.0f / (float)max(s1 - s0, 1);
        float ax = pf, ay = 0.f, bx = 0.f, by = 0.f;
        int i = s0;
        for (; i + 4 <= s1; i += 4) {
            int c0 = csr[i], c1 = csr[i + 1], c2 = csr[i + 2], c3 = csr[i + 3];
            float2 v0 = gsl2[(size_t)c0 * 4 + f2];
            float2 v1 = gsl2[(size_t)c1 * 4 + f2];
            float2 v2 = gsl2[(size_t)c2 * 4 + f2];
            float2 v3 = gsl2[(size_t)c3 * 4 + f2];
            ax += v0.x + v1.x; ay += v0.y + v1.y;
            bx += v2.x + v3.x; by += v2.y + v3.y;
        }
        for (; i < s1; ++i) {
            float2 v = gsl2[(size_t)csr[i] * 4 + f2];
            ax += v.x; ay += v.y;
        }
        float2 o;
        o.x = (ax + bx) * inv;
        o.y = (ay + by) * inv;
        asl2[(size_t)n * 4 + f2] = o;
    }
}

// ---------------- SAGE linear (+ReLU): one THREAD per node ----------------
__global__ void __launch_bounds__(256) k_lin3(const float* __restrict__ aggT,
        const float* __restrict__ rootT,
        const float* __restrict__ Wl, const float* __restrict__ bl,
        const float* __restrict__ Wr, float* __restrict__ outT) {
    int tid = blockIdx.x * 256 + threadIdx.x;
    int n = tid < NN ? tid : NN - 1;   // clamp; store guarded

    float acc[64];
#pragma unroll
    for (int d = 0; d < 64; ++d) acc[d] = bl[d];

    const float4* ap = (const float4*)(aggT + (size_t)n * 8);
    const float4* rp = (const float4*)(rootT + (size_t)n * 8);
    const size_t cstep = (size_t)NN * 2;   // chunk stride in float4s

    float4 a0 = ap[0], a1 = ap[1], r0 = rp[0], r1 = rp[1];
    for (int c = 0; c < 8; ++c) {
        float av[8] = {a0.x, a0.y, a0.z, a0.w, a1.x, a1.y, a1.z, a1.w};
        float rv[8] = {r0.x, r0.y, r0.z, r0.w, r1.x, r1.y, r1.z, r1.w};
        if (c < 7) {
            size_t off = (size_t)(c + 1) * cstep;
            a0 = ap[off]; a1 = ap[off + 1];
            r0 = rp[off]; r1 = rp[off + 1];
        }
        const float* wlc = Wl + c * 8;   // row d, cols c*8..c*8+7
        const float* wrc = Wr + c * 8;
#pragma unroll
        for (int d = 0; d < 64; ++d) {
#pragma unroll
            for (int k = 0; k < 8; ++k) {
                acc[d] += av[k] * wlc[d * 64 + k];
                acc[d] += rv[k] * wrc[d * 64 + k];
            }
        }
    }

    if (tid < NN) {
#pragma unroll
        for (int c = 0; c < 8; ++c) {
            float4 o0, o1;
            o0.x = fmaxf(acc[c * 8 + 0], 0.f); o0.y = fmaxf(acc[c * 8 + 1], 0.f);
            o0.z = fmaxf(acc[c * 8 + 2], 0.f); o0.w = fmaxf(acc[c * 8 + 3], 0.f);
            o1.x = fmaxf(acc[c * 8 + 4], 0.f); o1.y = fmaxf(acc[c * 8 + 5], 0.f);
            o1.z = fmaxf(acc[c * 8 + 6], 0.f); o1.w = fmaxf(acc[c * 8 + 7], 0.f);
            float4* op = (float4*)(outT + (size_t)c * NN * 8 + (size_t)n * 8);
            op[0] = o0; op[1] = o1;
        }
    }
}

// ---------------- per-graph mean-pool from h2 slabs (batch sorted) ----------------
__global__ void __launch_bounds__(256) k_pools(const float* __restrict__ hT,
        const int* __restrict__ batch, float* __restrict__ pooled) {
    int lane = threadIdx.x & 63;
    int wave = threadIdx.x >> 6;
    int n0 = blockIdx.x * 256 + wave * 64;
    if (n0 >= NN) return;
    const float* base = hT + (size_t)(lane >> 3) * NN * 8 + (lane & 7);
    int gcur = batch[n0];
    float rsum = 0.f;
    int nend = min(n0 + 64, NN);
    for (int n = n0; n < nend; ++n) {
        float v = base[(size_t)n * 8];
        int g = batch[n];
        if (g != gcur) {
            atomAddF(&pooled[(size_t)gcur * D + lane], rsum);
            rsum = 0.f; gcur = g;
        }
        rsum += v;
    }
    atomAddF(&pooled[(size_t)gcur * D + lane], rsum);
}

// ---------------- readout ----------------
__global__ void __launch_bounds__(256) k_bounds(const int* __restrict__ batch, int* __restrict__ gs) {
    int n = blockIdx.x * blockDim.x + threadIdx.x;
    if (n >= NN) return;
    int b = batch[n];
    if (n == 0) {
        for (int g = 0; g <= b; ++g) gs[g] = 0;
    } else {
        int bp = batch[n - 1];
        for (int g = bp + 1; g <= b; ++g) gs[g] = n;
    }
    if (n == NN - 1) {
        for (int g = b + 1; g <= NG; ++g) gs[g] = NN;
    }
}

__global__ void __launch_bounds__(256) k_out(const int* __restrict__ gs,
        const float* __restrict__ pooled, const float* __restrict__ Wout,
        const float* __restrict__ bout, float* __restrict__ out) {
    int lane = threadIdx.x & 63;
    int wave = threadIdx.x >> 6;
    int g = blockIdx.x * 4 + wave;       // 512 blocks
    int s0 = gs[g], s1 = gs[g + 1];
    float p = pooled[(size_t)g * D + lane] / (float)max(s1 - s0, 1);
    float c0 = p * Wout[lane];
    float c1 = p * Wout[D + lane];
#pragma unroll
    for (int off = 32; off > 0; off >>= 1) {
        c0 += __shfl_down(c0, off, 64);
        c1 += __shfl_down(c1, off, 64);
    }
    if (lane == 0) {
        out[g * C + 0] = c0 + bout[0];
        out[g * C + 1] = c1 + bout[1];
    }
}

extern "C" void kernel_launch(void* const* d_in, const int* in_sizes, int n_in,
                              void* d_out, int out_size, void* d_ws, size_t ws_size,
                              hipStream_t stream) {
    const int*   x     = (const int*)d_in[0];
    const int*   src   = (const int*)d_in[1];
    const int*   dst   = src + NE;
    const int*   batch = (const int*)d_in[2];
    const float* emb   = (const float*)d_in[3];
    const float* W1l   = (const float*)d_in[4];
    const float* b1l   = (const float*)d_in[5];
    const float* W1r   = (const float*)d_in[6];
    const float* W2l   = (const float*)d_in[7];
    const float* b2l   = (const float*)d_in[8];
    const float* W2r   = (const float*)d_in[9];
    const float* Wout  = (const float*)d_in[10];
    const float* bout  = (const float*)d_in[11];
    float* out = (float*)d_out;

    float* T0     = (float*)d_ws;                 // NN*64  h0 -> h1 slabs (in place)
    float* TA     = T0 + (size_t)NN * 64;         // NN*64  agg slabs -> h2 slabs (in place)
    float* pooled = TA + (size_t)NN * 64;         // NG*64
    int* bcur   = (int*)(pooled + (size_t)NG * 64);  // NBK  (contiguous w/ pooled for memset)
    int* bstart = bcur + NBK;                        // NBK+1
    int* startA = bstart + NBK + 1;                  // NN+1
    int* gs     = startA + NN + 1;                   // NG+1
    int* csr    = gs + NG + 1;                       // NE
    unsigned* barr = (unsigned*)(csr + NE);          // NBK*SLOT (~5.6 MB)

    hipMemsetAsync(pooled, 0, ((size_t)NG * 64 + NBK) * sizeof(float), stream);

    k_bucket<<<192, 256, 0, stream>>>(src, dst, bcur, barr);
    k_bscan <<<1, 256, 0, stream>>>(bcur, bstart, startA);
    k_sortb <<<NBK, 256, 0, stream>>>(bcur, bstart, barr, startA, csr);
    k_bounds<<<(NN + 255) / 256, 256, 0, stream>>>(batch, gs);
    k_embedT<<<(NN * 64 + 255) / 256, 256, 0, stream>>>(x, emb, T0);

    // ---- layer 1 ----
    k_agg2<<<((NN + 127) / 128) * 8, 256, 0, stream>>>(startA, csr, T0, TA);
    k_lin3<<<(NN + 255) / 256, 256, 0, stream>>>(TA, T0, W1l, b1l, W1r, T0);
    // ---- layer 2 ----
    k_agg2<<<((NN + 127) / 128) * 8, 256, 0, stream>>>(startA, csr, T0, TA);
    k_lin3<<<(NN + 255) / 256, 256, 0, stream>>>(TA, T0, W2l, b2l, W2r, TA);

    // ---- readout ----
    k_pools<<<(NN + 255) / 256, 256, 0, stream>>>(TA, batch, pooled);
    k_out<<<NG / 4, 256, 0, stream>>>(gs, pooled, Wout, bout, out);
}